// Round 10
// baseline (92.233 us; speedup 1.0000x reference)
//
#include <hip/hip_runtime.h>
#include <stdint.h>

#define NB   8
#define NN   2048
#define FIN  128
#define FOUT 64

__device__ __forceinline__ uint32_t rotl32(uint32_t x, uint32_t r) {
  return (x << r) | (x >> (32u - r));
}

// JAX threefry2x32 with key = (0, 42)
__device__ __forceinline__ void threefry_0_42(uint32_t x0, uint32_t x1,
                                              uint32_t& o0, uint32_t& o1) {
  const uint32_t k0 = 0u, k1 = 42u;
  const uint32_t k2 = 0x1BD11BDAu ^ k0 ^ k1;
  x0 += k0; x1 += k1;
#define TFR(r) { x0 += x1; x1 = rotl32(x1, r); x1 ^= x0; }
  TFR(13u) TFR(15u) TFR(26u) TFR(6u)   x0 += k1; x1 += k2 + 1u;
  TFR(17u) TFR(29u) TFR(16u) TFR(24u)  x0 += k2; x1 += k0 + 2u;
  TFR(13u) TFR(15u) TFR(26u) TFR(6u)   x0 += k0; x1 += k1 + 3u;
  TFR(17u) TFR(29u) TFR(16u) TFR(24u)  x0 += k1; x1 += k2 + 4u;
  TFR(13u) TFR(15u) TFR(26u) TFR(6u)   x0 += k2; x1 += k0 + 5u;
#undef TFR
  o0 = x0; o1 = x1;
}

// Partitionable threefry: bits = o0^o1 of threefry(key, 0, v); keep iff bit31==0.
__device__ __forceinline__ bool keep_bit(uint32_t v) {
  uint32_t o0, o1;
  threefry_0_42(0u, v, o0, o1);
  return !((o0 ^ o1) >> 31);
}

// Kernel A: Wh = h @ W, Wh1 = Wh@a[:64], Wh2 = Wh@a[64:]
// 4 rows/wave, scalar accumulators (proven ~5 us).
__global__ __launch_bounds__(256) void wh_kernel(
    const float* __restrict__ h, const float* __restrict__ W,
    const float* __restrict__ a, float* __restrict__ Wh,
    float* __restrict__ Wh1, float* __restrict__ Wh2) {
  __shared__ __align__(16) float wLds[FIN * FOUT];   // 32 KB
  __shared__ __align__(16) float hLds[16][FIN];      // 8 KB
  const int t = threadIdx.x;
  const int wv = t >> 6, lane = t & 63;
  const int rbase = blockIdx.x * 16;
  {
    const float4* W4 = reinterpret_cast<const float4*>(W);
    float4* wL4 = reinterpret_cast<float4*>(wLds);
    for (int idx = t; idx < FIN * FOUT / 4; idx += 256) wL4[idx] = W4[idx];
    const float4* h4 = reinterpret_cast<const float4*>(h + (size_t)rbase * FIN);
    float4* hL4 = reinterpret_cast<float4*>(&hLds[0][0]);
    for (int idx = t; idx < 16 * FIN / 4; idx += 256) hL4[idx] = h4[idx];
  }
  __syncthreads();
  const int r0 = wv * 4;
  float acc0 = 0.f, acc1 = 0.f, acc2 = 0.f, acc3 = 0.f;
#pragma unroll 4
  for (int k = 0; k < FIN; ++k) {
    const float w = wLds[k * FOUT + lane];
    acc0 += hLds[r0 + 0][k] * w;
    acc1 += hLds[r0 + 1][k] * w;
    acc2 += hLds[r0 + 2][k] * w;
    acc3 += hLds[r0 + 3][k] * w;
  }
  const float a1 = a[lane], a2 = a[FOUT + lane];
  float accs[4] = {acc0, acc1, acc2, acc3};
#pragma unroll
  for (int r = 0; r < 4; ++r) {
    const int row = rbase + r0 + r;
    Wh[(size_t)row * FOUT + lane] = accs[r];
    float x1 = accs[r] * a1, x2 = accs[r] * a2;
#pragma unroll
    for (int off = 32; off >= 1; off >>= 1) {
      x1 += __shfl_xor(x1, off);
      x2 += __shfl_xor(x2, off);
    }
    if (lane == 0) { Wh1[row] = x1; Wh2[row] = x2; }
  }
}

// Kernel B v5: ONE WAVE per row, 2 rows per wave (sequential), 32 elem/lane.
// Zero LDS, zero __syncthreads, shfl-only. 2048 long-lived blocks.
// exp phase overwrites ww[k] <- p (static idx). PV tail: UNCAPPED per-k
// ballot walk (fixes r9 bug: compressed-regime rows (wh1+mW<0) have ~30-100
// survivors because leaky-relu scales gaps by 0.2; the 64-slot capture
// dropped some — including, on peaked rows, the dominant one).
// Per survivor: wave-uniform keep_bit, p via __shfl(ww[k], src) (k is
// compile-time), coalesced 256 B Wh-row fma.
__global__ __launch_bounds__(256, 4) void attn_kernel(
    const int* __restrict__ adj, const float* __restrict__ Wh,
    const float* __restrict__ Wh1, const float* __restrict__ Wh2,
    float* __restrict__ out) {
  const int t = threadIdx.x;
  const int wv = t >> 6, lane = t & 63;
  const int wgid = blockIdx.x * 4 + wv;      // 0..8191

#pragma unroll 1
  for (int rr = 0; rr < 2; ++rr) {
    const int r = wgid + rr * 8192;          // row = b*NN + i
    const int b = r >> 11;
    const float wh1 = Wh1[r];
    const int*   arow = adj + (size_t)r * NN;
    const float* wrow = Wh2 + (size_t)b * NN;

    // masked Wh2 -> ww[32]; masked elems become +0.0 (mW >= 0; since the
    // connected max >= 0 w.p. 1 and softmax is shift-invariant, exact).
    float ww[32];
    float mW = 0.0f;
#pragma unroll
    for (int c = 0; c < 8; ++c) {
      const int4   av = *reinterpret_cast<const int4*>(arow + c * 256 + lane * 4);
      const float4 w4 = *reinterpret_cast<const float4*>(wrow + c * 256 + lane * 4);
      const float f0 = __int_as_float(__float_as_int(w4.x) & (-av.x));
      const float f1 = __int_as_float(__float_as_int(w4.y) & (-av.y));
      const float f2 = __int_as_float(__float_as_int(w4.z) & (-av.z));
      const float f3 = __int_as_float(__float_as_int(w4.w) & (-av.w));
      ww[c * 4 + 0] = f0; ww[c * 4 + 1] = f1;
      ww[c * 4 + 2] = f2; ww[c * 4 + 3] = f3;
      mW = fmaxf(mW, fmaxf(fmaxf(f0, f1), fmaxf(f2, f3)));
    }
#pragma unroll
    for (int off = 1; off < 64; off <<= 1) mW = fmaxf(mW, __shfl_xor(mW, off));

    const float me_arg = wh1 + mW;
    const float me = fmaxf(me_arg, 0.2f * me_arg);   // LR(wh1+mW) = row max of e
    const float c1 = wh1 - me;
    const float c2 = fmaf(0.2f, wh1, -me);

    // exp phase: p = exp(LR(wh1+ww)-me) = exp(max(c1+ww, fma(.2,ww,c2)))
    float s = 0.f;
#pragma unroll
    for (int k = 0; k < 32; ++k) {
      const float u1 = c1 + ww[k];
      const float u2 = fmaf(0.2f, ww[k], c2);
      const float p = __expf(fmaxf(u1, u2));   // masked -> exp(~-260) = 0
      s += p;
      ww[k] = p;                               // overwrite, static index
    }
#pragma unroll
    for (int off = 1; off < 64; off <<= 1) s += __shfl_xor(s, off);
    const float inv = 2.0f / s;                // dropout 1/(1-p)=2 folded in

    // PV: uncapped per-k ballot walk over survivors (p > 1e-10)
    float acc = 0.f;
    const uint32_t vbase = (uint32_t)r << 11;
#pragma unroll
    for (int k = 0; k < 32; ++k) {
      unsigned long long km = __ballot(ww[k] > 1e-10f);
      while (km) {
        const int src = __builtin_ctzll(km);
        km &= km - 1;
        const int j = ((k >> 2) << 8) + (src << 2) + (k & 3);
        if (keep_bit(vbase | (uint32_t)j)) {         // wave-uniform
          const float cc = __shfl(ww[k], src) * inv; // k compile-time
          acc += cc * Wh[((size_t)(b * NN + j)) * FOUT + lane];
        }
      }
    }
    out[(size_t)r * FOUT + lane] = acc;
  }
}

extern "C" void kernel_launch(void* const* d_in, const int* in_sizes, int n_in,
                              void* d_out, int out_size, void* d_ws, size_t ws_size,
                              hipStream_t stream) {
  const float* h   = (const float*)d_in[0];
  const int*   adj = (const int*)d_in[1];
  const float* W   = (const float*)d_in[2];
  const float* a   = (const float*)d_in[3];
  float* out = (float*)d_out;
  float* ws  = (float*)d_ws;

  float* Wh  = ws;                                 // 16384*64 floats
  float* Wh1 = ws + (size_t)NB * NN * FOUT;        // 16384
  float* Wh2 = Wh1 + NB * NN;                      // 16384

  wh_kernel<<<dim3((NB * NN) / 16), dim3(256), 0, stream>>>(h, W, a, Wh, Wh1, Wh2);
  attn_kernel<<<dim3(2048), dim3(256), 0, stream>>>(adj, Wh, Wh1, Wh2, out);
}

// Round 11
// 58.230 us; speedup vs baseline: 1.5839x; 1.5839x over previous
//
#include <hip/hip_runtime.h>
#include <stdint.h>

#define NB   8
#define NN   2048
#define FIN  128
#define FOUT 64
#define MAXS 512

__device__ __forceinline__ uint32_t rotl32(uint32_t x, uint32_t r) {
  return (x << r) | (x >> (32u - r));
}

// JAX threefry2x32 with key = (0, 42)
__device__ __forceinline__ void threefry_0_42(uint32_t x0, uint32_t x1,
                                              uint32_t& o0, uint32_t& o1) {
  const uint32_t k0 = 0u, k1 = 42u;
  const uint32_t k2 = 0x1BD11BDAu ^ k0 ^ k1;
  x0 += k0; x1 += k1;
#define TFR(r) { x0 += x1; x1 = rotl32(x1, r); x1 ^= x0; }
  TFR(13u) TFR(15u) TFR(26u) TFR(6u)   x0 += k1; x1 += k2 + 1u;
  TFR(17u) TFR(29u) TFR(16u) TFR(24u)  x0 += k2; x1 += k0 + 2u;
  TFR(13u) TFR(15u) TFR(26u) TFR(6u)   x0 += k0; x1 += k1 + 3u;
  TFR(17u) TFR(29u) TFR(16u) TFR(24u)  x0 += k1; x1 += k2 + 4u;
  TFR(13u) TFR(15u) TFR(26u) TFR(6u)   x0 += k2; x1 += k0 + 5u;
#undef TFR
  o0 = x0; o1 = x1;
}

// Partitionable threefry: bits = o0^o1 of threefry(key, 0, v); keep iff bit31==0.
__device__ __forceinline__ bool keep_bit(uint32_t v) {
  uint32_t o0, o1;
  threefry_0_42(0u, v, o0, o1);
  return !((o0 ^ o1) >> 31);
}

// Kernel A: Wh = h @ W, Wh1 = Wh@a[:64], Wh2 = Wh@a[64:]
// 4 rows/wave, scalar accumulators (proven ~5 us).
__global__ __launch_bounds__(256) void wh_kernel(
    const float* __restrict__ h, const float* __restrict__ W,
    const float* __restrict__ a, float* __restrict__ Wh,
    float* __restrict__ Wh1, float* __restrict__ Wh2) {
  __shared__ __align__(16) float wLds[FIN * FOUT];   // 32 KB
  __shared__ __align__(16) float hLds[16][FIN];      // 8 KB
  const int t = threadIdx.x;
  const int wv = t >> 6, lane = t & 63;
  const int rbase = blockIdx.x * 16;
  {
    const float4* W4 = reinterpret_cast<const float4*>(W);
    float4* wL4 = reinterpret_cast<float4*>(wLds);
    for (int idx = t; idx < FIN * FOUT / 4; idx += 256) wL4[idx] = W4[idx];
    const float4* h4 = reinterpret_cast<const float4*>(h + (size_t)rbase * FIN);
    float4* hL4 = reinterpret_cast<float4*>(&hLds[0][0]);
    for (int idx = t; idx < 16 * FIN / 4; idx += 256) hL4[idx] = h4[idx];
  }
  __syncthreads();
  const int r0 = wv * 4;
  float acc0 = 0.f, acc1 = 0.f, acc2 = 0.f, acc3 = 0.f;
#pragma unroll 4
  for (int k = 0; k < FIN; ++k) {
    const float w = wLds[k * FOUT + lane];
    acc0 += hLds[r0 + 0][k] * w;
    acc1 += hLds[r0 + 1][k] * w;
    acc2 += hLds[r0 + 2][k] * w;
    acc3 += hLds[r0 + 3][k] * w;
  }
  const float a1 = a[lane], a2 = a[FOUT + lane];
  float accs[4] = {acc0, acc1, acc2, acc3};
#pragma unroll
  for (int r = 0; r < 4; ++r) {
    const int row = rbase + r0 + r;
    Wh[(size_t)row * FOUT + lane] = accs[r];
    float x1 = accs[r] * a1, x2 = accs[r] * a2;
#pragma unroll
    for (int off = 32; off >= 1; off >>= 1) {
      x1 += __shfl_xor(x1, off);
      x2 += __shfl_xor(x2, off);
    }
    if (lane == 0) { Wh1[row] = x1; Wh2[row] = x2; }
  }
}

// Kernel B (r3 structure, proven ~31 us, + micro-trims):
// 8192 blocks x 256 thr; block = batch pair (b, b+4), row i; 8 elem/thread/row.
// Trims vs r3: int-mask + folded-constant exp (r10-proven math, 6 VALU/elem,
// no divergent gate — r4's gate cost +15 us), threefry fused into PV walk
// (one less barrier + LDS pass). 3 barriers total.
__global__ __launch_bounds__(256) void attn_kernel(
    const int* __restrict__ adj, const float* __restrict__ Wh,
    const float* __restrict__ Wh1, const float* __restrict__ Wh2,
    float* __restrict__ out) {
  __shared__ float mredA[2][4], sredA[2][4];
  __shared__ int cnt[2];
  __shared__ int   survJ[2][MAXS];   // 4 KB
  __shared__ float survP[2][MAXS];   // 4 KB
  __shared__ float accL[2][4][FOUT]; // 2 KB

  const int i = blockIdx.x & (NN - 1);
  const int b = blockIdx.x >> 11;                 // 0..3
  const int b2 = b + 4;
  const int t = threadIdx.x;
  const int wv = t >> 6, lane = t & 63;

  const float wh1_0 = Wh1[b * NN + i];
  const float wh1_1 = Wh1[b2 * NN + i];
  const size_t adjBase0 = ((size_t)(b * NN) + i) * NN;
  const size_t adjBase1 = ((size_t)(b2 * NN) + i) * NN;
  const int jA = t * 4;            // chunk 0: [0, 1024)
  const int jB = 1024 + t * 4;     // chunk 1: [1024, 2048)

  // 8 loads up front (dense 1 KB per wave-instruction)
  const int4   aA0 = *reinterpret_cast<const int4*>(adj + adjBase0 + jA);
  const int4   aB0 = *reinterpret_cast<const int4*>(adj + adjBase0 + jB);
  const int4   aA1 = *reinterpret_cast<const int4*>(adj + adjBase1 + jA);
  const int4   aB1 = *reinterpret_cast<const int4*>(adj + adjBase1 + jB);
  const float4 wA0 = *reinterpret_cast<const float4*>(Wh2 + (size_t)b * NN + jA);
  const float4 wB0 = *reinterpret_cast<const float4*>(Wh2 + (size_t)b * NN + jB);
  const float4 wA1 = *reinterpret_cast<const float4*>(Wh2 + (size_t)b2 * NN + jA);
  const float4 wB1 = *reinterpret_cast<const float4*>(Wh2 + (size_t)b2 * NN + jB);

  // int-mask: disconnected -> +0.0 (mW = max(connected,0); shift-invariant,
  // masked p = exp(LR(wh1)-me) <= exp(-0.2*mW) ~ e^-58: negligible in s,
  // below survivor threshold. r10-proven.)
  float ww0[8], ww1[8];
  ww0[0] = __int_as_float(__float_as_int(wA0.x) & (-aA0.x));
  ww0[1] = __int_as_float(__float_as_int(wA0.y) & (-aA0.y));
  ww0[2] = __int_as_float(__float_as_int(wA0.z) & (-aA0.z));
  ww0[3] = __int_as_float(__float_as_int(wA0.w) & (-aA0.w));
  ww0[4] = __int_as_float(__float_as_int(wB0.x) & (-aB0.x));
  ww0[5] = __int_as_float(__float_as_int(wB0.y) & (-aB0.y));
  ww0[6] = __int_as_float(__float_as_int(wB0.z) & (-aB0.z));
  ww0[7] = __int_as_float(__float_as_int(wB0.w) & (-aB0.w));
  ww1[0] = __int_as_float(__float_as_int(wA1.x) & (-aA1.x));
  ww1[1] = __int_as_float(__float_as_int(wA1.y) & (-aA1.y));
  ww1[2] = __int_as_float(__float_as_int(wA1.z) & (-aA1.z));
  ww1[3] = __int_as_float(__float_as_int(wA1.w) & (-aA1.w));
  ww1[4] = __int_as_float(__float_as_int(wB1.x) & (-aB1.x));
  ww1[5] = __int_as_float(__float_as_int(wB1.y) & (-aB1.y));
  ww1[6] = __int_as_float(__float_as_int(wB1.z) & (-aB1.z));
  ww1[7] = __int_as_float(__float_as_int(wB1.w) & (-aB1.w));

  float mW0 = 0.f, mW1 = 0.f;
#pragma unroll
  for (int e = 0; e < 8; ++e) {
    mW0 = fmaxf(mW0, ww0[e]);
    mW1 = fmaxf(mW1, ww1[e]);
  }
#pragma unroll
  for (int off = 1; off < 64; off <<= 1) {
    mW0 = fmaxf(mW0, __shfl_xor(mW0, off));
    mW1 = fmaxf(mW1, __shfl_xor(mW1, off));
  }
  if (lane == 0) { mredA[0][wv] = mW0; mredA[1][wv] = mW1; }
  if (t < 2) cnt[t] = 0;
  __syncthreads();
  mW0 = fmaxf(fmaxf(mredA[0][0], mredA[0][1]), fmaxf(mredA[0][2], mredA[0][3]));
  mW1 = fmaxf(fmaxf(mredA[1][0], mredA[1][1]), fmaxf(mredA[1][2], mredA[1][3]));

  const float me0 = fmaxf(wh1_0 + mW0, 0.2f * (wh1_0 + mW0));  // row max of e
  const float me1 = fmaxf(wh1_1 + mW1, 0.2f * (wh1_1 + mW1));
  const float c10 = wh1_0 - me0, c20 = fmaf(0.2f, wh1_0, -me0);
  const float c11 = wh1_1 - me1, c21 = fmaf(0.2f, wh1_1, -me1);

  // unconditional exp + compaction (p = exp(LR(wh1+w)-me))
  float s0 = 0.f, s1 = 0.f;
#pragma unroll
  for (int k = 0; k < 8; ++k) {
    const int j = (k < 4) ? (jA + k) : (jB + k - 4);
    const float p0 = __expf(fmaxf(c10 + ww0[k], fmaf(0.2f, ww0[k], c20)));
    s0 += p0;
    if (p0 > 1e-10f) {
      const int idx = atomicAdd(&cnt[0], 1);
      if (idx < MAXS) { survJ[0][idx] = j; survP[0][idx] = p0; }
    }
    const float p1 = __expf(fmaxf(c11 + ww1[k], fmaf(0.2f, ww1[k], c21)));
    s1 += p1;
    if (p1 > 1e-10f) {
      const int idx = atomicAdd(&cnt[1], 1);
      if (idx < MAXS) { survJ[1][idx] = j; survP[1][idx] = p1; }
    }
  }
#pragma unroll
  for (int off = 1; off < 64; off <<= 1) {
    s0 += __shfl_xor(s0, off);
    s1 += __shfl_xor(s1, off);
  }
  if (lane == 0) { sredA[0][wv] = s0; sredA[1][wv] = s1; }
  __syncthreads();
  s0 = sredA[0][0] + sredA[0][1] + sredA[0][2] + sredA[0][3];
  s1 = sredA[1][0] + sredA[1][1] + sredA[1][2] + sredA[1][3];
  const float inv0 = 2.0f / s0;   // dropout 1/(1-p)=2 folded in
  const float inv1 = 2.0f / s1;
  const int c0v = min(cnt[0], MAXS), c1v = min(cnt[1], MAXS);

  // fused dropout + sparse PV (keep_bit wave-uniform per survivor)
  float acc0 = 0.f, acc1 = 0.f;
  const uint32_t r0v = (uint32_t)(b * NN + i) << 11;
  const uint32_t r1v = (uint32_t)(b2 * NN + i) << 11;
  for (int idx = wv; idx < c0v; idx += 4) {
    const int j = survJ[0][idx];
    if (keep_bit(r0v | (uint32_t)j)) {
      const float cc = survP[0][idx] * inv0;
      acc0 += cc * Wh[((size_t)(b * NN + j)) * FOUT + lane];
    }
  }
  for (int idx = wv; idx < c1v; idx += 4) {
    const int j = survJ[1][idx];
    if (keep_bit(r1v | (uint32_t)j)) {
      const float cc = survP[1][idx] * inv1;
      acc1 += cc * Wh[((size_t)(b2 * NN + j)) * FOUT + lane];
    }
  }
  accL[0][wv][lane] = acc0;
  accL[1][wv][lane] = acc1;
  __syncthreads();
  if (t < 128) {
    const int bb = t >> 6, f = t & 63;
    const float r = accL[bb][0][f] + accL[bb][1][f] + accL[bb][2][f] + accL[bb][3][f];
    const int bo = (bb == 0) ? b : b2;
    out[((size_t)bo * NN + i) * FOUT + f] = r;
  }
}

extern "C" void kernel_launch(void* const* d_in, const int* in_sizes, int n_in,
                              void* d_out, int out_size, void* d_ws, size_t ws_size,
                              hipStream_t stream) {
  const float* h   = (const float*)d_in[0];
  const int*   adj = (const int*)d_in[1];
  const float* W   = (const float*)d_in[2];
  const float* a   = (const float*)d_in[3];
  float* out = (float*)d_out;
  float* ws  = (float*)d_ws;

  float* Wh  = ws;                                 // 16384*64 floats
  float* Wh1 = ws + (size_t)NB * NN * FOUT;        // 16384
  float* Wh2 = Wh1 + NB * NN;                      // 16384

  wh_kernel<<<dim3((NB * NN) / 16), dim3(256), 0, stream>>>(h, W, a, Wh, Wh1, Wh2);
  attn_kernel<<<dim3((NB / 2) * NN), dim3(256), 0, stream>>>(adj, Wh, Wh1, Wh2, out);
}

// Round 12
// 57.142 us; speedup vs baseline: 1.6141x; 1.0190x over previous
//
#include <hip/hip_runtime.h>
#include <stdint.h>

#define NB   8
#define NN   2048
#define FIN  128
#define FOUT 64
#define MAXS 512

__device__ __forceinline__ uint32_t rotl32(uint32_t x, uint32_t r) {
  return (x << r) | (x >> (32u - r));
}

// JAX threefry2x32 with key = (0, 42)
__device__ __forceinline__ void threefry_0_42(uint32_t x0, uint32_t x1,
                                              uint32_t& o0, uint32_t& o1) {
  const uint32_t k0 = 0u, k1 = 42u;
  const uint32_t k2 = 0x1BD11BDAu ^ k0 ^ k1;
  x0 += k0; x1 += k1;
#define TFR(r) { x0 += x1; x1 = rotl32(x1, r); x1 ^= x0; }
  TFR(13u) TFR(15u) TFR(26u) TFR(6u)   x0 += k1; x1 += k2 + 1u;
  TFR(17u) TFR(29u) TFR(16u) TFR(24u)  x0 += k2; x1 += k0 + 2u;
  TFR(13u) TFR(15u) TFR(26u) TFR(6u)   x0 += k0; x1 += k1 + 3u;
  TFR(17u) TFR(29u) TFR(16u) TFR(24u)  x0 += k1; x1 += k2 + 4u;
  TFR(13u) TFR(15u) TFR(26u) TFR(6u)   x0 += k2; x1 += k0 + 5u;
#undef TFR
  o0 = x0; o1 = x1;
}

// Partitionable threefry: bits = o0^o1 of threefry(key, 0, v); keep iff bit31==0.
__device__ __forceinline__ bool keep_bit(uint32_t v) {
  uint32_t o0, o1;
  threefry_0_42(0u, v, o0, o1);
  return !((o0 ^ o1) >> 31);
}

// Kernel A: Wh = h @ W, Wh1 = Wh@a[:64], Wh2 = Wh@a[64:]
// 4 rows/wave, scalar accumulators (proven ~5 us).
__global__ __launch_bounds__(256) void wh_kernel(
    const float* __restrict__ h, const float* __restrict__ W,
    const float* __restrict__ a, float* __restrict__ Wh,
    float* __restrict__ Wh1, float* __restrict__ Wh2) {
  __shared__ __align__(16) float wLds[FIN * FOUT];   // 32 KB
  __shared__ __align__(16) float hLds[16][FIN];      // 8 KB
  const int t = threadIdx.x;
  const int wv = t >> 6, lane = t & 63;
  const int rbase = blockIdx.x * 16;
  {
    const float4* W4 = reinterpret_cast<const float4*>(W);
    float4* wL4 = reinterpret_cast<float4*>(wLds);
    for (int idx = t; idx < FIN * FOUT / 4; idx += 256) wL4[idx] = W4[idx];
    const float4* h4 = reinterpret_cast<const float4*>(h + (size_t)rbase * FIN);
    float4* hL4 = reinterpret_cast<float4*>(&hLds[0][0]);
    for (int idx = t; idx < 16 * FIN / 4; idx += 256) hL4[idx] = h4[idx];
  }
  __syncthreads();
  const int r0 = wv * 4;
  float acc0 = 0.f, acc1 = 0.f, acc2 = 0.f, acc3 = 0.f;
#pragma unroll 4
  for (int k = 0; k < FIN; ++k) {
    const float w = wLds[k * FOUT + lane];
    acc0 += hLds[r0 + 0][k] * w;
    acc1 += hLds[r0 + 1][k] * w;
    acc2 += hLds[r0 + 2][k] * w;
    acc3 += hLds[r0 + 3][k] * w;
  }
  const float a1 = a[lane], a2 = a[FOUT + lane];
  float accs[4] = {acc0, acc1, acc2, acc3};
#pragma unroll
  for (int r = 0; r < 4; ++r) {
    const int row = rbase + r0 + r;
    Wh[(size_t)row * FOUT + lane] = accs[r];
    float x1 = accs[r] * a1, x2 = accs[r] * a2;
#pragma unroll
    for (int off = 32; off >= 1; off >>= 1) {
      x1 += __shfl_xor(x1, off);
      x2 += __shfl_xor(x2, off);
    }
    if (lane == 0) { Wh1[row] = x1; Wh2[row] = x2; }
  }
}

// Kernel B v7: 2048 long-lived blocks; each loops 4 units (row-pairs).
// Per unit = proven r6/r11 body: up-front loads, int-mask, m-reduce,
// unconditional exp + LDS compaction, s-reduce, PARALLEL threefry phase
// (one survivor per thread — r11's wave-serial fusion cost +6 us),
// PV with zero-skip. Fixed per-block costs amortized 4x (r2 calibration:
// ~1500 instr/thread ran at 95% VALUBusy; ~370 ran at ~50%).
__global__ __launch_bounds__(256) void attn_kernel(
    const int* __restrict__ adj, const float* __restrict__ Wh,
    const float* __restrict__ Wh1, const float* __restrict__ Wh2,
    float* __restrict__ out) {
  __shared__ float mredA[2][4], sredA[2][4];
  __shared__ int cnt[2];
  __shared__ int   survJ[2][MAXS];   // 4 KB
  __shared__ float survP[2][MAXS];   // 4 KB
  __shared__ float accL[2][4][FOUT]; // 2 KB

  const int t = threadIdx.x;
  const int wv = t >> 6, lane = t & 63;
  const int jA = t * 4;            // chunk 0: [0, 1024)
  const int jB = 1024 + t * 4;     // chunk 1: [1024, 2048)

#pragma unroll 1
  for (int u = 0; u < 4; ++u) {
    const int unit = (int)blockIdx.x + u * 2048;  // 0..8191
    const int i = unit & (NN - 1);
    const int b = unit >> 11;                     // 0..3
    const int b2 = b + 4;

    const float wh1_0 = Wh1[b * NN + i];
    const float wh1_1 = Wh1[b2 * NN + i];
    const size_t adjBase0 = ((size_t)(b * NN) + i) * NN;
    const size_t adjBase1 = ((size_t)(b2 * NN) + i) * NN;

    // 8 loads up front (dense 1 KB per wave-instruction)
    const int4   aA0 = *reinterpret_cast<const int4*>(adj + adjBase0 + jA);
    const int4   aB0 = *reinterpret_cast<const int4*>(adj + adjBase0 + jB);
    const int4   aA1 = *reinterpret_cast<const int4*>(adj + adjBase1 + jA);
    const int4   aB1 = *reinterpret_cast<const int4*>(adj + adjBase1 + jB);
    const float4 wA0 = *reinterpret_cast<const float4*>(Wh2 + (size_t)b * NN + jA);
    const float4 wB0 = *reinterpret_cast<const float4*>(Wh2 + (size_t)b * NN + jB);
    const float4 wA1 = *reinterpret_cast<const float4*>(Wh2 + (size_t)b2 * NN + jA);
    const float4 wB1 = *reinterpret_cast<const float4*>(Wh2 + (size_t)b2 * NN + jB);

    // int-mask: disconnected -> +0.0 (mW = max(connected,0); shift-invariant;
    // masked p <= e^-58: negligible in s, below survivor threshold. r10-proven.)
    float ww0[8], ww1[8];
    ww0[0] = __int_as_float(__float_as_int(wA0.x) & (-aA0.x));
    ww0[1] = __int_as_float(__float_as_int(wA0.y) & (-aA0.y));
    ww0[2] = __int_as_float(__float_as_int(wA0.z) & (-aA0.z));
    ww0[3] = __int_as_float(__float_as_int(wA0.w) & (-aA0.w));
    ww0[4] = __int_as_float(__float_as_int(wB0.x) & (-aB0.x));
    ww0[5] = __int_as_float(__float_as_int(wB0.y) & (-aB0.y));
    ww0[6] = __int_as_float(__float_as_int(wB0.z) & (-aB0.z));
    ww0[7] = __int_as_float(__float_as_int(wB0.w) & (-aB0.w));
    ww1[0] = __int_as_float(__float_as_int(wA1.x) & (-aA1.x));
    ww1[1] = __int_as_float(__float_as_int(wA1.y) & (-aA1.y));
    ww1[2] = __int_as_float(__float_as_int(wA1.z) & (-aA1.z));
    ww1[3] = __int_as_float(__float_as_int(wA1.w) & (-aA1.w));
    ww1[4] = __int_as_float(__float_as_int(wB1.x) & (-aB1.x));
    ww1[5] = __int_as_float(__float_as_int(wB1.y) & (-aB1.y));
    ww1[6] = __int_as_float(__float_as_int(wB1.z) & (-aB1.z));
    ww1[7] = __int_as_float(__float_as_int(wB1.w) & (-aB1.w));

    float mW0 = 0.f, mW1 = 0.f;
#pragma unroll
    for (int e = 0; e < 8; ++e) {
      mW0 = fmaxf(mW0, ww0[e]);
      mW1 = fmaxf(mW1, ww1[e]);
    }
#pragma unroll
    for (int off = 1; off < 64; off <<= 1) {
      mW0 = fmaxf(mW0, __shfl_xor(mW0, off));
      mW1 = fmaxf(mW1, __shfl_xor(mW1, off));
    }
    if (lane == 0) { mredA[0][wv] = mW0; mredA[1][wv] = mW1; }
    if (t < 2) cnt[t] = 0;
    __syncthreads();                               // barrier 1
    mW0 = fmaxf(fmaxf(mredA[0][0], mredA[0][1]), fmaxf(mredA[0][2], mredA[0][3]));
    mW1 = fmaxf(fmaxf(mredA[1][0], mredA[1][1]), fmaxf(mredA[1][2], mredA[1][3]));

    const float me0 = fmaxf(wh1_0 + mW0, 0.2f * (wh1_0 + mW0));  // row max of e
    const float me1 = fmaxf(wh1_1 + mW1, 0.2f * (wh1_1 + mW1));
    const float c10 = wh1_0 - me0, c20 = fmaf(0.2f, wh1_0, -me0);
    const float c11 = wh1_1 - me1, c21 = fmaf(0.2f, wh1_1, -me1);

    // unconditional exp + compaction (p = exp(LR(wh1+w)-me))
    float s0 = 0.f, s1 = 0.f;
#pragma unroll
    for (int k = 0; k < 8; ++k) {
      const int j = (k < 4) ? (jA + k) : (jB + k - 4);
      const float p0 = __expf(fmaxf(c10 + ww0[k], fmaf(0.2f, ww0[k], c20)));
      s0 += p0;
      if (p0 > 1e-10f) {
        const int idx = atomicAdd(&cnt[0], 1);
        if (idx < MAXS) { survJ[0][idx] = j; survP[0][idx] = p0; }
      }
      const float p1 = __expf(fmaxf(c11 + ww1[k], fmaf(0.2f, ww1[k], c21)));
      s1 += p1;
      if (p1 > 1e-10f) {
        const int idx = atomicAdd(&cnt[1], 1);
        if (idx < MAXS) { survJ[1][idx] = j; survP[1][idx] = p1; }
      }
    }
#pragma unroll
    for (int off = 1; off < 64; off <<= 1) {
      s0 += __shfl_xor(s0, off);
      s1 += __shfl_xor(s1, off);
    }
    if (lane == 0) { sredA[0][wv] = s0; sredA[1][wv] = s1; }
    __syncthreads();                               // barrier 2
    s0 = sredA[0][0] + sredA[0][1] + sredA[0][2] + sredA[0][3];
    s1 = sredA[1][0] + sredA[1][1] + sredA[1][2] + sredA[1][3];
    const float inv0 = 2.0f / s0;   // dropout 1/(1-p)=2 folded in
    const float inv1 = 2.0f / s1;
    const int c0v = min(cnt[0], MAXS), c1v = min(cnt[1], MAXS);

    // phase 3: PARALLEL lazy dropout — one survivor per thread
    const uint32_t r0v = (uint32_t)(b * NN + i) << 11;
    const uint32_t r1v = (uint32_t)(b2 * NN + i) << 11;
    for (int idx = t; idx < c0v; idx += 256) {
      survP[0][idx] = keep_bit(r0v | (uint32_t)survJ[0][idx])
                        ? survP[0][idx] * inv0 : 0.f;
    }
    for (int idx = t; idx < c1v; idx += 256) {
      survP[1][idx] = keep_bit(r1v | (uint32_t)survJ[1][idx])
                        ? survP[1][idx] * inv1 : 0.f;
    }
    __syncthreads();                               // barrier 3

    // phase 4: sparse PV with zero-skip
    float acc0 = 0.f, acc1 = 0.f;
    for (int idx = wv; idx < c0v; idx += 4) {
      const float c = survP[0][idx];
      if (c != 0.f)
        acc0 += c * Wh[((size_t)(b * NN + survJ[0][idx])) * FOUT + lane];
    }
    for (int idx = wv; idx < c1v; idx += 4) {
      const float c = survP[1][idx];
      if (c != 0.f)
        acc1 += c * Wh[((size_t)(b2 * NN + survJ[1][idx])) * FOUT + lane];
    }
    accL[0][wv][lane] = acc0;
    accL[1][wv][lane] = acc1;
    __syncthreads();                               // barrier 4
    if (t < 128) {
      const int bb = t >> 6, f = t & 63;
      const float r = accL[bb][0][f] + accL[bb][1][f] + accL[bb][2][f] + accL[bb][3][f];
      const int bo = (bb == 0) ? b : b2;
      out[((size_t)bo * NN + i) * FOUT + f] = r;
    }
    // next unit's first LDS writes (mredA/cnt) are fenced by barrier 1;
    // accL reads above are by the same threads that write it next -> safe.
  }
}

extern "C" void kernel_launch(void* const* d_in, const int* in_sizes, int n_in,
                              void* d_out, int out_size, void* d_ws, size_t ws_size,
                              hipStream_t stream) {
  const float* h   = (const float*)d_in[0];
  const int*   adj = (const int*)d_in[1];
  const float* W   = (const float*)d_in[2];
  const float* a   = (const float*)d_in[3];
  float* out = (float*)d_out;
  float* ws  = (float*)d_ws;

  float* Wh  = ws;                                 // 16384*64 floats
  float* Wh1 = ws + (size_t)NB * NN * FOUT;        // 16384
  float* Wh2 = Wh1 + NB * NN;                      // 16384

  wh_kernel<<<dim3((NB * NN) / 16), dim3(256), 0, stream>>>(h, W, a, Wh, Wh1, Wh2);
  attn_kernel<<<dim3(2048), dim3(256), 0, stream>>>(adj, Wh, Wh1, Wh2, out);
}